// Round 11
// baseline (189.287 us; speedup 1.0000x reference)
//
#include <hip/hip_runtime.h>
#include <math.h>

namespace {

constexpr int Himg = 224, Wimg = 224, Cn = 3, Kk = 32;
constexpr int MAXT = 64;
constexpr int WSTRIDE = 512;               // ints per image in tap workspace
constexpr int IMG_F  = Himg * Wimg * Cn;   // 150528 floats per image
constexpr int ROW_F  = Wimg * Cn;          // 672 floats per row
constexpr int ROW_B  = ROW_F * 4;          // 2688 B

// ---- sliding-window persistent tiles ----
// Model (R0-R10): loads ~73 cyc/wave-instr/CU (MSHR rate); stores free;
// ds_read_b32 ~5.8 cyc/slot; blur time = DS-compute + staging with poor
// cross-block overlap (lockstep blocks). R11: 768 persistent blocks
// (b, tx, yhalf), each slides a 59-row window over 4 tiles of TH=28 rows:
// shift 31 rows in LDS, stage only 28 new rows, loads issued to REGS
// BEFORE compute so VMEM hides under DS compute. Compute identical to R10.
constexpr int TW_F = 224;                  // tile width in float-cols (672 = 3*224)
constexpr int TH   = 28;                   // output rows per tile step (224 = 8*28)
constexpr int TILES_X = 3;
constexpr int TPB  = 4;                    // tile steps per block (8 tiles / 2 halves)
constexpr int RH   = TH / 2;               // 14 rows per thread
constexpr int L_W  = 320;                  // 224 + 2*48 halo
constexpr int L_H  = TH + 31;              // 59 rows (dky in [-15,16], +13 rows depth)
constexpr int L_SZ = L_W * L_H;            // 18880 floats = 75520 B -> 2 blocks/CU
constexpr int SH_ROWS = L_H - TH;          // 31 rows kept across a slide
constexpr int SH_CH   = SH_ROWS * 80;      // 2480 v4-chunks to shift
constexpr int NEW_CH  = TH * 80;           // 2240 v4-chunks staged per step
constexpr int PRO_CH  = L_H * 80;          // 4720 v4-chunks staged in prologue

typedef float v4  __attribute__((ext_vector_type(4), aligned(4)));
typedef float v4a __attribute__((ext_vector_type(4), aligned(16)));

// ws per-image layout (ints): [0]=n  [1]=w  [2..65]=dky  [66..129]=dkx  [130..193]=xoff(bytes)

// ---------------- pre-pass: one tap list per image ----------------
__global__ __launch_bounds__(64)
void build_taps(const float* __restrict__ tbl,
                const int* __restrict__ amt,
                const int* __restrict__ ang,
                int* __restrict__ ws)
{
    const int b   = blockIdx.x;
    const int tid = threadIdx.x;

    __shared__ int   s_cnt;
    __shared__ float s_w;
    __shared__ int   s_dky[MAXT], s_dkx[MAXT];

    if (tid == 0) { s_cnt = 0; s_w = 0.0f; }
    __syncthreads();

    const int a = amt[b];
    // reference-exact numerics (verified absmax 0.0039 across all prior rounds)
    const float  rad = (float)ang[b] * (float)(M_PI / 180.0);
    const double rd  = (double)rad;
    const float  cth = (float)cos(rd);
    const float  sth = (float)sin(rd);
    const float  e   = 31.0f;
    const float xoff = __fmul_rn(__fsub_rn(e, __fsub_rn(__fmul_rn(cth, e), __fmul_rn(sth, e))), 0.5f);
    const float yoff = __fmul_rn(__fsub_rn(e, __fadd_rn(__fmul_rn(sth, e), __fmul_rn(cth, e))), 0.5f);

    for (int p = tid; p < Kk * Kk; p += 64) {
        const int   ky = p >> 5, kx = p & 31;
        const float xf = (float)kx, yf = (float)ky;
        const float sx = __fadd_rn(__fsub_rn(__fmul_rn(cth, xf), __fmul_rn(sth, yf)), xoff);
        const float sy = __fadd_rn(__fadd_rn(__fmul_rn(sth, xf), __fmul_rn(cth, yf)), yoff);
        const int ix = (int)rintf(sx);   // round-half-even == jnp.round
        const int iy = (int)rintf(sy);
        if (ix >= 0 && ix < Kk && iy >= 0 && iy < Kk) {
            const float v = tbl[((a * Kk + iy) * Kk + ix) * Cn];
            if (v != 0.0f) {
                const int idx = atomicAdd(&s_cnt, 1);
                if (idx < MAXT) {
                    s_dky[idx] = ky - 15;
                    s_dkx[idx] = kx - 15;
                    s_w = v;                 // benign race: all writers store 1/size
                }
            }
        }
    }
    __syncthreads();

    const int n = min(s_cnt, MAXT);
    int* wsb = ws + b * WSTRIDE;
    if (tid == 0) { wsb[0] = n; wsb[1] = __float_as_int(s_w); }
    for (int i = tid; i < n; i += 64) {
        wsb[2 + i]   = s_dky[i];
        wsb[66 + i]  = s_dkx[i];
        wsb[130 + i] = s_dky[i] * ROW_B + s_dkx[i] * (int)(Cn * sizeof(float));
    }
}

// ---------------- sliding-window LDS conv ----------------
// Per tile step: (1) issue next 28 rows -> regs (early, hides under compute);
// (2) compute tile (R10 pattern: 1 uniform v_add/tap + 14 static-offset b32
// reads + adds, zero-padded window -> no masks, tap-ascending adds);
// (3) shift-read the 31 surviving rows to regs; barrier; (4) write shifted
// rows + staged rows; barrier. All LDS contents & add order == R10 -> bitwise
// identical output.
__global__ __launch_bounds__(512, 2)
void blur_slide(const float* __restrict__ x,
                const int* __restrict__ ws,
                float* __restrict__ out,
                int B)
{
    const int tid = threadIdx.x;
    const int L   = blockIdx.x;

    // XCD-pinned decode: image b handled entirely by XCD (b & 7). 768 = 8*96.
    int b, rem;
    if (B == 128) {
        const int xcd = L & 7;
        const int j   = L >> 3;            // [0, 96)
        const int g   = j / 6;             // image group on this XCD
        rem = j - g * 6;
        b   = g * 8 + xcd;
    } else {
        b   = L / 6;
        rem = L - b * 6;
    }
    const int tx    = rem >> 1;            // 0..2
    const int yhalf = rem & 1;             // 0: tiles 0-3, 1: tiles 4-7
    const int tyBeg = yhalf * TPB;
    const int g0 = tx * TW_F - 48;         // global float-col of LDS col 0 (mult of 4)

    __shared__ float lds[L_SZ];            // 75520 B
    __shared__ int   shNW[2];
    __shared__ int   s_tof[MAXT + 1];

    const int* wsb = ws + b * WSTRIDE;
    if (tid < 2)    shNW[tid] = wsb[tid];
    if (tid < MAXT) {
        const int dky = wsb[2 + tid];
        const int dkx = wsb[66 + tid];
        s_tof[tid] = (dky * L_W + 3 * dkx) * 4;   // bytes
    }

    const float* xb = x + (size_t)b * IMG_F;

    // ---- prologue: stage full 59-row window for the first tile ----
    {
        const int r0 = tyBeg * TH - 15;
        for (int u = tid; u < PRO_CH; u += 512) {
            const int lr  = u / 80;
            const int lc4 = (u - lr * 80) * 4;
            const int gr  = r0 + lr;
            const int gc  = g0 + lc4;
            const bool ok = (unsigned)gr < (unsigned)Himg && (unsigned)gc < (unsigned)ROW_F;
            const float* sp = ok ? (xb + (size_t)gr * ROW_F + gc) : xb;   // safe addr
            const v4 tv = *(const v4a*)sp;
            *(v4a*)(&lds[4 * u]) = ok ? tv : v4{0, 0, 0, 0};              // linear dst
        }
    }
    __syncthreads();

    const int   n = shNW[0];
    const float w = __int_as_float(shNW[1]);
    const int rhalf = tid >> 8;            // waves 0-3: rows 0..13; waves 4-7: 14..27
    const int col   = tid - (rhalf << 8);  // 0..255, active if < 224

    for (int t = 0; t < TPB; ++t) {
        const int y0 = (tyBeg + t) * TH;

        // ---- (1) issue-early: next step's 28 new rows (y0+44 .. y0+71) -> regs ----
        v4 rv0{0,0,0,0}, rv1{0,0,0,0}, rv2{0,0,0,0}, rv3{0,0,0,0}, rv4{0,0,0,0};
        if (t < TPB - 1) {
#pragma unroll
            for (int j = 0; j < 5; ++j) {
                const int v = tid + 512 * j;
                if (v < NEW_CH) {
                    const int rr  = v / 80;
                    const int cc4 = (v - rr * 80) * 4;
                    const int gr  = y0 + TH + 16 + rr;
                    const int gc  = g0 + cc4;
                    const bool ok = (unsigned)gr < (unsigned)Himg && (unsigned)gc < (unsigned)ROW_F;
                    const float* sp = ok ? (xb + (size_t)gr * ROW_F + gc) : xb;
                    v4 tv = *(const v4a*)sp;
                    tv = ok ? tv : v4{0, 0, 0, 0};
                    if (j == 0) rv0 = tv; else if (j == 1) rv1 = tv; else if (j == 2) rv2 = tv;
                    else if (j == 3) rv3 = tv; else rv4 = tv;
                }
            }
        }

        // ---- (2) compute + store (identical pattern to R10) ----
        if (col < TW_F) {
            const char* ldsb  = (const char*)lds;
            const int   abase = ((15 + rhalf * RH) * L_W + 48 + col) * 4;

            float acc[RH];
#pragma unroll
            for (int p = 0; p < RH; ++p) acc[p] = 0.0f;

            int tofn = s_tof[0];
            for (int i = 0; i < n; ++i) {
                const int tof = __builtin_amdgcn_readfirstlane(tofn);  // wave-uniform
                tofn = s_tof[i + 1];
                const char* ap = ldsb + (abase + tof);
#pragma unroll
                for (int p = 0; p < RH; ++p)
                    acc[p] += *(const float*)(ap + p * (L_W * 4));     // static offsets
            }

            float* ob = out + (size_t)b * IMG_F
                      + (size_t)(y0 + rhalf * RH) * ROW_F + tx * TW_F + col;
#pragma unroll
            for (int p = 0; p < RH; ++p)
                __builtin_nontemporal_store(acc[p] * w, ob + p * ROW_F);
        }
        if (t == TPB - 1) break;

        // ---- (3) shift-read: rows TH..58 -> regs (reads only; no barrier vs compute) ----
        v4 sv0{0,0,0,0}, sv1{0,0,0,0}, sv2{0,0,0,0}, sv3{0,0,0,0}, sv4{0,0,0,0};
#pragma unroll
        for (int j = 0; j < 5; ++j) {
            const int v = tid + 512 * j;
            if (v < SH_CH) {
                const v4 tv = *(const v4a*)(&lds[TH * L_W + 4 * v]);   // linear src
                if (j == 0) sv0 = tv; else if (j == 1) sv1 = tv; else if (j == 2) sv2 = tv;
                else if (j == 3) sv3 = tv; else sv4 = tv;
            }
        }
        __syncthreads();   // all compute + shift reads done

        // ---- (4) writes: shifted rows -> 0..30, staged rows -> 31..58 ----
#pragma unroll
        for (int j = 0; j < 5; ++j) {
            const int v = tid + 512 * j;
            if (v < SH_CH) {
                const v4 tv = (j == 0) ? sv0 : (j == 1) ? sv1 : (j == 2) ? sv2
                            : (j == 3) ? sv3 : sv4;
                *(v4a*)(&lds[4 * v]) = tv;
            }
        }
#pragma unroll
        for (int j = 0; j < 5; ++j) {
            const int v = tid + 512 * j;
            if (v < NEW_CH) {
                const v4 tv = (j == 0) ? rv0 : (j == 1) ? rv1 : (j == 2) ? rv2
                            : (j == 3) ? rv3 : rv4;
                *(v4a*)(&lds[SH_ROWS * L_W + 4 * v]) = tv;
            }
        }
        __syncthreads();   // window ready for next tile
    }
}

}  // namespace

extern "C" void kernel_launch(void* const* d_in, const int* in_sizes, int n_in,
                              void* d_out, int out_size, void* d_ws, size_t ws_size,
                              hipStream_t stream) {
    const float* x   = (const float*)d_in[0];
    const float* tbl = (const float*)d_in[1];
    const int*   amt = (const int*)d_in[2];
    const int*   ang = (const int*)d_in[3];
    float*       out = (float*)d_out;
    int*         ws  = (int*)d_ws;

    const int B = in_sizes[2];  // 128

    build_taps<<<B, 64, 0, stream>>>(tbl, amt, ang, ws);
    blur_slide<<<B * TILES_X * 2, 512, 0, stream>>>(x, ws, out, B);
}